// Round 1
// baseline (63485.541 us; speedup 1.0000x reference)
//
#include <hip/hip_runtime.h>
#include <math.h>

#define EPSF   1e-6f
#define REEPS  1e-4f

enum EigFn { F_LOG = 0, F_SQRT = 1, F_INVSQRT = 2, F_CLIP = 3, F_INVSQRTEXP = 4 };

__device__ __forceinline__ float eig_apply(float w, int f) {
    switch (f) {
        case F_LOG:        return logf(fmaxf(w, EPSF));
        case F_SQRT:       return sqrtf(fmaxf(w, EPSF));
        case F_INVSQRT:    return 1.0f / sqrtf(fmaxf(w, EPSF));
        case F_CLIP:       return fmaxf(w, REEPS);
        case F_INVSQRTEXP: return 1.0f / sqrtf(fmaxf(expf(w), EPSF));
        default:           return w;
    }
}

// ---------------------------------------------------------------------------
// f[b,t,n] = sum_k x[b,k,t]*fc_w[n,k] + fc_b[n], then centered over n (axis=2)
// x: (64,512,100), f: (64,100,100)
// ---------------------------------------------------------------------------
__global__ void __launch_bounds__(128) fc_kernel(
    const float* __restrict__ x, const float* __restrict__ fcw,
    const float* __restrict__ fcb, float* __restrict__ f)
{
    __shared__ float xc[512];
    __shared__ float fv[100];
    __shared__ float red[128];
    const int bt = blockIdx.x;
    const int b = bt / 100, t = bt % 100;
    const int tid = threadIdx.x, nt = blockDim.x;

    for (int k = tid; k < 512; k += nt)
        xc[k] = x[(size_t)b * 51200 + (size_t)k * 100 + t];
    __syncthreads();

    float val = 0.f;
    if (tid < 100) {
        float acc = fcb[tid];
        const float* wr = fcw + (size_t)tid * 512;
        #pragma unroll 8
        for (int k = 0; k < 512; ++k) acc += xc[k] * wr[k];
        val = acc;
        fv[tid] = acc;
    }
    __syncthreads();
    float part = 0.f;
    for (int i = tid; i < 100; i += nt) part += fv[i];
    red[tid] = part; __syncthreads();
    for (int s = nt >> 1; s > 0; s >>= 1) {
        if (tid < s) red[tid] += red[tid + s];
        __syncthreads();
    }
    float m = red[0] * 0.01f;
    if (tid < 100)
        f[(size_t)b * 10000 + t * 100 + tid] = val - m;
}

// ---------------------------------------------------------------------------
// cov[b] = f[b]^T f[b] / 99 + 1e-5*trace*I   (f[b]: 100x100, (t,n))
// ---------------------------------------------------------------------------
__global__ void __launch_bounds__(256) cov_kernel(
    const float* __restrict__ f, float* __restrict__ cov)
{
    __shared__ float fl[10000];
    __shared__ float cl[10000];
    __shared__ float red[256];
    const int b = blockIdx.x, tid = threadIdx.x, nt = blockDim.x;
    const float* fp = f + (size_t)b * 10000;
    for (int i = tid; i < 10000; i += nt) fl[i] = fp[i];
    __syncthreads();
    for (int idx = tid; idx < 10000; idx += nt) {
        int n = idx / 100, mcol = idx - n * 100;
        float acc = 0.f;
        #pragma unroll 4
        for (int t = 0; t < 100; ++t) acc += fl[t * 100 + n] * fl[t * 100 + mcol];
        cl[idx] = acc * (1.0f / 99.0f);
    }
    __syncthreads();
    float tr = 0.f;
    for (int i = tid; i < 100; i += nt) tr += cl[i * 100 + i];
    red[tid] = tr; __syncthreads();
    for (int s = nt >> 1; s > 0; s >>= 1) {
        if (tid < s) red[tid] += red[tid + s];
        __syncthreads();
    }
    float lam = red[0] * 1e-5f;
    float* cp = cov + (size_t)b * 10000;
    for (int idx = tid; idx < 10000; idx += nt) {
        int n = idx / 100, mcol = idx - n * 100;
        cp[idx] = cl[idx] + ((n == mcol) ? lam : 0.f);
    }
}

// ---------------------------------------------------------------------------
// out[id] = sym( W[wi] @ X[xi] @ W[wi]^T ),  W: (*, NO, NI), X: (*, NI, NI)
// id = blockIdx.x = b*cout + co ; xi = b*cin + (co % cin)
// wi = per_matrix ? id : co
// ---------------------------------------------------------------------------
template <int NI, int NO>
__global__ void __launch_bounds__(256) triple_kernel(
    const float* __restrict__ W, const float* __restrict__ X,
    float* __restrict__ out, int cin, int cout, int per_matrix)
{
    __shared__ float Xs[NI * NI];
    __shared__ float T1[NO * NI];
    __shared__ float Ys[NO * NO];
    const int tid = threadIdx.x, nt = blockDim.x;
    const int id = blockIdx.x;
    const int b = id / cout, co = id - b * cout;
    const float* Xp = X + (size_t)(b * cin + (co % cin)) * NI * NI;
    const float* Wp = W + (size_t)(per_matrix ? id : co) * NO * NI;

    for (int idx = tid; idx < NI * NI; idx += nt) Xs[idx] = Xp[idx];
    __syncthreads();
    for (int idx = tid; idx < NO * NI; idx += nt) {
        int r = idx / NI, k = idx - r * NI;
        const float* wr = Wp + (size_t)r * NI;
        float acc = 0.f;
        #pragma unroll 4
        for (int j = 0; j < NI; ++j) acc += wr[j] * Xs[j * NI + k];
        T1[idx] = acc;
    }
    __syncthreads();
    for (int idx = tid; idx < NO * NO; idx += nt) {
        int r = idx / NO, c2 = idx - r * NO;
        const float* t1r = T1 + (size_t)r * NI;
        const float* wc = Wp + (size_t)c2 * NI;
        float acc = 0.f;
        #pragma unroll 4
        for (int k = 0; k < NI; ++k) acc += t1r[k] * wc[k];
        Ys[idx] = acc;
    }
    __syncthreads();
    float* Op = out + (size_t)id * NO * NO;
    for (int idx = tid; idx < NO * NO; idx += nt) {
        int r = idx / NO, c2 = idx - r * NO;
        Op[idx] = 0.5f * (Ys[idx] + Ys[c2 * NO + r]);
    }
}

// ---------------------------------------------------------------------------
// out[c] = mean_b in[b,c]   in: (B,C,nn), out: (C,nn)
// ---------------------------------------------------------------------------
__global__ void __launch_bounds__(256) mean_kernel(
    const float* __restrict__ in, float* __restrict__ out, int B, int C, int nn)
{
    const int c = blockIdx.x;
    for (int idx = threadIdx.x; idx < nn; idx += blockDim.x) {
        float acc = 0.f;
        for (int b = 0; b < B; ++b) acc += in[((size_t)b * C + c) * nn + idx];
        out[(size_t)c * nn + idx] = acc * (1.0f / 64.0f);
    }
}

// ---------------------------------------------------------------------------
// Batched cyclic Jacobi symmetric eigendecomposition + spectral function.
// One block per matrix. out{1,2}[i][j] = sum_k V[i][k] f(w_k) V[j][k].
// Destination: b = mat/C, c = mat%C -> out + b*out_bstride + (cbase+c)*N*N
// ---------------------------------------------------------------------------
template <int N>
__global__ void __launch_bounds__(256) jacobi_kernel(
    const float* __restrict__ src,
    float* __restrict__ out1, int f1,
    float* __restrict__ out2, int f2,
    int out_bstride, int cbase, int C)
{
    constexpr int M = N / 2;
    constexpr int LD = N + 1;
    __shared__ float A[N * LD];
    __shared__ float V[N * LD];
    __shared__ float cs_[M], sn_[M];
    __shared__ int pr_[M], qr_[M];
    __shared__ int arr[N];
    __shared__ float raww[N], fw[N];
    __shared__ float red[256];
    __shared__ int anyrot;
    __shared__ float thrfloor;

    const int tid = threadIdx.x, nt = blockDim.x;
    const int mat = blockIdx.x;
    const float* Sp = src + (size_t)mat * N * N;

    float sq = 0.f;
    for (int idx = tid; idx < N * N; idx += nt) {
        int i = idx / N, j = idx - i * N;
        float v = 0.5f * (Sp[idx] + Sp[j * N + i]);
        A[i * LD + j] = v;
        V[i * LD + j] = (i == j) ? 1.f : 0.f;
        sq += v * v;
    }
    for (int idx = tid; idx < N; idx += nt) arr[idx] = idx;
    red[tid] = sq; __syncthreads();
    for (int s = nt >> 1; s > 0; s >>= 1) {
        if (tid < s) red[tid] += red[tid + s];
        __syncthreads();
    }
    if (tid == 0) thrfloor = 1e-7f * sqrtf(red[0]);
    __syncthreads();
    const float tf = thrfloor;

    for (int sweep = 0; sweep < 30; ++sweep) {
        if (tid == 0) anyrot = 0;
        __syncthreads();
        for (int round = 0; round < N - 1; ++round) {
            if (tid < M) {
                int p = arr[tid], q = arr[N - 1 - tid];
                if (p > q) { int t = p; p = q; q = t; }
                float app = A[p * LD + p], aqq = A[q * LD + q], apq = A[p * LD + q];
                float c = 1.f, s = 0.f;
                float thr = fmaxf(1e-7f * sqrtf(fabsf(app * aqq)), tf);
                if (fabsf(apq) > thr) {
                    anyrot = 1;
                    float tau = (aqq - app) / (2.f * apq);
                    float den = fabsf(tau) + sqrtf(1.f + tau * tau);
                    float t = ((tau >= 0.f) ? 1.f : -1.f) / den;   // tau=inf -> t=0
                    c = 1.f / sqrtf(1.f + t * t);
                    s = t * c;
                }
                cs_[tid] = c; sn_[tid] = s; pr_[tid] = p; qr_[tid] = q;
            }
            __syncthreads();
            // rows: A <- J^T A
            for (int idx = tid; idx < M * N; idx += nt) {
                int i = idx / N, j = idx - i * N;
                float s = sn_[i];
                if (s != 0.f) {
                    float c = cs_[i];
                    int p = pr_[i], q = qr_[i];
                    float ap = A[p * LD + j], aq = A[q * LD + j];
                    A[p * LD + j] = c * ap - s * aq;
                    A[q * LD + j] = s * ap + c * aq;
                }
            }
            __syncthreads();
            // cols: A <- A J ; V <- V J
            for (int idx = tid; idx < M * N; idx += nt) {
                int i = idx / N, j = idx - i * N;
                float s = sn_[i];
                if (s != 0.f) {
                    float c = cs_[i];
                    int p = pr_[i], q = qr_[i];
                    float ap = A[j * LD + p], aq = A[j * LD + q];
                    A[j * LD + p] = c * ap - s * aq;
                    A[j * LD + q] = s * ap + c * aq;
                    float vp = V[j * LD + p], vq = V[j * LD + q];
                    V[j * LD + p] = c * vp - s * vq;
                    V[j * LD + q] = s * vp + c * vq;
                }
            }
            __syncthreads();
            // rotate tournament: arr[0] fixed, arr[1..N-1] rotate right
            int nv = 0;
            bool hv = (tid >= 1 && tid < N);
            if (hv) nv = (tid == 1) ? arr[N - 1] : arr[tid - 1];
            __syncthreads();
            if (hv) arr[tid] = nv;
            __syncthreads();
        }
        int done = (anyrot == 0);
        __syncthreads();
        if (done) break;
    }
    __syncthreads();

    for (int idx = tid; idx < N; idx += nt) raww[idx] = A[idx * LD + idx];
    __syncthreads();

    const int bb = mat / C, cc = mat - bb * C;
    // pass 1
    for (int idx = tid; idx < N; idx += nt) fw[idx] = eig_apply(raww[idx], f1);
    __syncthreads();
    for (int idx = tid; idx < N * N; idx += nt) {
        int i = idx / N, k = idx - i * N;
        A[i * LD + k] = V[i * LD + k] * fw[k];
    }
    __syncthreads();
    {
        float* o = out1 + (size_t)bb * out_bstride + (size_t)(cbase + cc) * N * N;
        for (int idx = tid; idx < N * N; idx += nt) {
            int i = idx / N, j = idx - i * N;
            float acc = 0.f;
            #pragma unroll 4
            for (int k = 0; k < N; ++k) acc += A[i * LD + k] * V[j * LD + k];
            o[idx] = acc;
        }
    }
    if (out2) {
        __syncthreads();
        for (int idx = tid; idx < N; idx += nt) fw[idx] = eig_apply(raww[idx], f2);
        __syncthreads();
        for (int idx = tid; idx < N * N; idx += nt) {
            int i = idx / N, k = idx - i * N;
            A[i * LD + k] = V[i * LD + k] * fw[k];
        }
        __syncthreads();
        float* o = out2 + (size_t)bb * out_bstride + (size_t)(cbase + cc) * N * N;
        for (int idx = tid; idx < N * N; idx += nt) {
            int i = idx / N, j = idx - i * N;
            float acc = 0.f;
            #pragma unroll 4
            for (int k = 0; k < N; ++k) acc += A[i * LD + k] * V[j * LD + k];
            o[idx] = acc;
        }
    }
}

// ---------------------------------------------------------------------------
// out[b,n] = sum_k Lc[b,k]*cls_w[n,k] + cls_b[n]   (64,20000)@(20000,100)
// ---------------------------------------------------------------------------
__global__ void __launch_bounds__(256) head_kernel(
    const float* __restrict__ Lc, const float* __restrict__ cw,
    const float* __restrict__ cb, float* __restrict__ out)
{
    __shared__ float row[20000];
    const int b = blockIdx.x, tid = threadIdx.x, nt = blockDim.x;
    const float* lp = Lc + (size_t)b * 20000;
    for (int i = tid; i < 20000; i += nt) row[i] = lp[i];
    __syncthreads();
    if (tid < 100) {
        float acc = cb[tid];
        const float* wr = cw + (size_t)tid * 20000;
        #pragma unroll 4
        for (int k = 0; k < 20000; ++k) acc += row[k] * wr[k];
        out[b * 100 + tid] = acc;
    }
}

// ---------------------------------------------------------------------------
extern "C" void kernel_launch(void* const* d_in, const int* in_sizes, int n_in,
                              void* d_out, int out_size, void* d_ws, size_t ws_size,
                              hipStream_t stream)
{
    const float* x      = (const float*)d_in[0];
    const float* fc_w   = (const float*)d_in[1];
    const float* fc_b   = (const float*)d_in[2];
    const float* stem_w = (const float*)d_in[3];
    const float* pre0_w = (const float*)d_in[4];
    const float* pre1_w = (const float*)d_in[5];
    const float* wr0    = (const float*)d_in[6];
    const float* wr1    = (const float*)d_in[7];
    const float* wn2    = (const float*)d_in[8];
    const float* wn4    = (const float*)d_in[9];
    const float* wn7    = (const float*)d_in[10];
    const float* cls_w  = (const float*)d_in[11];
    const float* cls_b  = (const float*)d_in[12];
    float* out = (float*)d_out;
    float* ws  = (float*)d_ws;

    // workspace layout (floats); total high-water = 5,800,000 f = 23.2 MB
    float* F    = ws + 0;        // (64,100,100) fc output
    float* COV  = ws + 640000;   // (64,100,100)
    float* Y    = ws + 1280000;  // up to (64,2,100,100)
    float* L    = ws + 2560000;  // up to (64,2,100,100)
    float* S0   = ws + 3840000;  // (64,2,100,100)
    float* S1   = ws + 0;        // (64,2,100,100)  reuses F (dead)
    float* Sst  = ws + 0;        // (64,1,100,100)  reuses F (dead)
    float* R    = ws + 640000;   // (64,1,100,100)  reuses COV (dead)
    float* bA   = ws + 1280000;  // (64,2,50,50) each from here
    float* bB   = ws + 1600000;
    float* bAs  = ws + 1920000;
    float* bAis = ws + 2240000;
    float* bIn  = ws + 2560000;
    float* bSi  = ws + 2880000;
    float* s2b  = ws + 3200000;
    float* s3b  = ws + 3520000;
    float* s4b  = ws + 3840000;
    float* s5b  = ws + 4160000;
    float* Lc   = ws + 4480000;  // (64,8,50,50) = (64,20000)
    float* Mm   = ws + 5760000;  // (2,100,100) max
    float* Gi   = ws + 5780000;  // (2,100,100) max

    // stage 0: features + covariance
    fc_kernel<<<dim3(6400), dim3(128), 0, stream>>>(x, fc_w, fc_b, F);
    cov_kernel<<<dim3(64), dim3(256), 0, stream>>>(F, COV);

    // stem: s = batchnorm_spd(bimap(cov, stem_w))
    triple_kernel<100,100><<<dim3(64), dim3(256), 0, stream>>>(stem_w, COV, Y, 1, 1, 0);
    jacobi_kernel<100><<<dim3(64), dim3(256), 0, stream>>>(Y, L, F_LOG, nullptr, 0, 10000, 0, 1);
    mean_kernel<<<dim3(1), dim3(256), 0, stream>>>(L, Mm, 64, 1, 10000);
    jacobi_kernel<100><<<dim3(1), dim3(256), 0, stream>>>(Mm, Gi, F_INVSQRTEXP, nullptr, 0, 10000, 0, 1);
    triple_kernel<100,100><<<dim3(64), dim3(256), 0, stream>>>(Gi, Y, Sst, 1, 1, 0);

    // r = reeig(s)
    jacobi_kernel<100><<<dim3(64), dim3(256), 0, stream>>>(Sst, R, F_CLIP, nullptr, 0, 10000, 0, 1);

    // branch 0: s0 = batchnorm_spd(bimap(r, pre0_w))
    triple_kernel<100,100><<<dim3(128), dim3(256), 0, stream>>>(pre0_w, R, Y, 1, 2, 0);
    jacobi_kernel<100><<<dim3(128), dim3(256), 0, stream>>>(Y, L, F_LOG, nullptr, 0, 20000, 0, 2);
    mean_kernel<<<dim3(2), dim3(256), 0, stream>>>(L, Mm, 64, 2, 10000);
    jacobi_kernel<100><<<dim3(2), dim3(256), 0, stream>>>(Mm, Gi, F_INVSQRTEXP, nullptr, 0, 10000, 0, 1);
    triple_kernel<100,100><<<dim3(128), dim3(256), 0, stream>>>(Gi, Y, S0, 2, 2, 0);

    // branch 1: s1 = batchnorm_spd(bimap(r, pre1_w))
    triple_kernel<100,100><<<dim3(128), dim3(256), 0, stream>>>(pre1_w, R, Y, 1, 2, 0);
    jacobi_kernel<100><<<dim3(128), dim3(256), 0, stream>>>(Y, L, F_LOG, nullptr, 0, 20000, 0, 2);
    mean_kernel<<<dim3(2), dim3(256), 0, stream>>>(L, Mm, 64, 2, 10000);
    jacobi_kernel<100><<<dim3(2), dim3(256), 0, stream>>>(Mm, Gi, F_INVSQRTEXP, nullptr, 0, 10000, 0, 1);
    triple_kernel<100,100><<<dim3(128), dim3(256), 0, stream>>>(Gi, Y, S1, 2, 2, 0);

    // states[2] = bary2(bimap(s0,wr0), bimap(s1,wr1))
    triple_kernel<100,50><<<dim3(128), dim3(256), 0, stream>>>(wr0, S0, bA, 2, 2, 0);
    triple_kernel<100,50><<<dim3(128), dim3(256), 0, stream>>>(wr1, S1, bB, 2, 2, 0);
    jacobi_kernel<50><<<dim3(128), dim3(128), 0, stream>>>(bA, bAs, F_SQRT, bAis, F_INVSQRT, 5000, 0, 2);
    triple_kernel<50,50><<<dim3(128), dim3(256), 0, stream>>>(bAis, bB, bIn, 2, 2, 1);
    jacobi_kernel<50><<<dim3(128), dim3(128), 0, stream>>>(bIn, bSi, F_SQRT, nullptr, 0, 5000, 0, 2);
    triple_kernel<50,50><<<dim3(128), dim3(256), 0, stream>>>(bAs, bSi, s2b, 2, 2, 1);

    // states[3] = bary2(bimap(s2,wn2), s2)
    triple_kernel<50,50><<<dim3(128), dim3(256), 0, stream>>>(wn2, s2b, bA, 2, 2, 0);
    jacobi_kernel<50><<<dim3(128), dim3(128), 0, stream>>>(bA, bAs, F_SQRT, bAis, F_INVSQRT, 5000, 0, 2);
    triple_kernel<50,50><<<dim3(128), dim3(256), 0, stream>>>(bAis, s2b, bIn, 2, 2, 1);
    jacobi_kernel<50><<<dim3(128), dim3(128), 0, stream>>>(bIn, bSi, F_SQRT, nullptr, 0, 5000, 0, 2);
    triple_kernel<50,50><<<dim3(128), dim3(256), 0, stream>>>(bAs, bSi, s3b, 2, 2, 1);

    // states[4] = bary2(bimap(s3,wn4), s2)
    triple_kernel<50,50><<<dim3(128), dim3(256), 0, stream>>>(wn4, s3b, bA, 2, 2, 0);
    jacobi_kernel<50><<<dim3(128), dim3(128), 0, stream>>>(bA, bAs, F_SQRT, bAis, F_INVSQRT, 5000, 0, 2);
    triple_kernel<50,50><<<dim3(128), dim3(256), 0, stream>>>(bAis, s2b, bIn, 2, 2, 1);
    jacobi_kernel<50><<<dim3(128), dim3(128), 0, stream>>>(bIn, bSi, F_SQRT, nullptr, 0, 5000, 0, 2);
    triple_kernel<50,50><<<dim3(128), dim3(256), 0, stream>>>(bAs, bSi, s4b, 2, 2, 1);

    // states[5] = bary2(s4, bimap(s3,wn7))
    triple_kernel<50,50><<<dim3(128), dim3(256), 0, stream>>>(wn7, s3b, bB, 2, 2, 0);
    jacobi_kernel<50><<<dim3(128), dim3(128), 0, stream>>>(s4b, bAs, F_SQRT, bAis, F_INVSQRT, 5000, 0, 2);
    triple_kernel<50,50><<<dim3(128), dim3(256), 0, stream>>>(bAis, bB, bIn, 2, 2, 1);
    jacobi_kernel<50><<<dim3(128), dim3(128), 0, stream>>>(bIn, bSi, F_SQRT, nullptr, 0, 5000, 0, 2);
    triple_kernel<50,50><<<dim3(128), dim3(256), 0, stream>>>(bAs, bSi, s5b, 2, 2, 1);

    // logm(concat(states[2:6])) -> Lc (64,8,50,50)
    jacobi_kernel<50><<<dim3(128), dim3(128), 0, stream>>>(s2b, Lc, F_LOG, nullptr, 0, 20000, 0, 2);
    jacobi_kernel<50><<<dim3(128), dim3(128), 0, stream>>>(s3b, Lc, F_LOG, nullptr, 0, 20000, 2, 2);
    jacobi_kernel<50><<<dim3(128), dim3(128), 0, stream>>>(s4b, Lc, F_LOG, nullptr, 0, 20000, 4, 2);
    jacobi_kernel<50><<<dim3(128), dim3(128), 0, stream>>>(s5b, Lc, F_LOG, nullptr, 0, 20000, 6, 2);

    // head
    head_kernel<<<dim3(64), dim3(256), 0, stream>>>(Lc, cls_w, cls_b, out);
}

// Round 2
// 47235.043 us; speedup vs baseline: 1.3440x; 1.3440x over previous
//
#include <hip/hip_runtime.h>
#include <math.h>

#define EPSF   1e-6f
#define REEPS  1e-4f

enum EigFn { F_LOG = 0, F_SQRT = 1, F_INVSQRT = 2, F_CLIP = 3, F_INVSQRTEXP = 4 };

__device__ __forceinline__ float eig_apply(float w, int f) {
    switch (f) {
        case F_LOG:        return logf(fmaxf(w, EPSF));
        case F_SQRT:       return sqrtf(fmaxf(w, EPSF));
        case F_INVSQRT:    return 1.0f / sqrtf(fmaxf(w, EPSF));
        case F_CLIP:       return fmaxf(w, REEPS);
        case F_INVSQRTEXP: return 1.0f / sqrtf(fmaxf(expf(w), EPSF));
        default:           return w;
    }
}

// ---------------------------------------------------------------------------
// f[b,t,n] = sum_k x[b,k,t]*fc_w[n,k] + fc_b[n], centered over n
// ---------------------------------------------------------------------------
__global__ void __launch_bounds__(128) fc_kernel(
    const float* __restrict__ x, const float* __restrict__ fcw,
    const float* __restrict__ fcb, float* __restrict__ f)
{
    __shared__ float xc[512];
    __shared__ float fv[100];
    __shared__ float red[128];
    const int bt = blockIdx.x;
    const int b = bt / 100, t = bt % 100;
    const int tid = threadIdx.x, nt = blockDim.x;

    for (int k = tid; k < 512; k += nt)
        xc[k] = x[(size_t)b * 51200 + (size_t)k * 100 + t];
    __syncthreads();

    float val = 0.f;
    if (tid < 100) {
        float acc = fcb[tid];
        const float* wr = fcw + (size_t)tid * 512;
        #pragma unroll 8
        for (int k = 0; k < 512; ++k) acc += xc[k] * wr[k];
        val = acc;
        fv[tid] = acc;
    }
    __syncthreads();
    float part = 0.f;
    for (int i = tid; i < 100; i += nt) part += fv[i];
    red[tid] = part; __syncthreads();
    for (int s = nt >> 1; s > 0; s >>= 1) {
        if (tid < s) red[tid] += red[tid + s];
        __syncthreads();
    }
    float m = red[0] * 0.01f;
    if (tid < 100)
        f[(size_t)b * 10000 + t * 100 + tid] = val - m;
}

// ---------------------------------------------------------------------------
// cov[b] = f[b]^T f[b] / 99 + 1e-5*trace*I
// ---------------------------------------------------------------------------
__global__ void __launch_bounds__(256) cov_kernel(
    const float* __restrict__ f, float* __restrict__ cov)
{
    __shared__ float fl[10000];
    __shared__ float cl[10000];
    __shared__ float red[256];
    const int b = blockIdx.x, tid = threadIdx.x, nt = blockDim.x;
    const float* fp = f + (size_t)b * 10000;
    for (int i = tid; i < 10000; i += nt) fl[i] = fp[i];
    __syncthreads();
    for (int idx = tid; idx < 10000; idx += nt) {
        int n = idx / 100, mcol = idx - n * 100;
        float acc = 0.f;
        #pragma unroll 4
        for (int t = 0; t < 100; ++t) acc += fl[t * 100 + n] * fl[t * 100 + mcol];
        cl[idx] = acc * (1.0f / 99.0f);
    }
    __syncthreads();
    float tr = 0.f;
    for (int i = tid; i < 100; i += nt) tr += cl[i * 100 + i];
    red[tid] = tr; __syncthreads();
    for (int s = nt >> 1; s > 0; s >>= 1) {
        if (tid < s) red[tid] += red[tid + s];
        __syncthreads();
    }
    float lam = red[0] * 1e-5f;
    float* cp = cov + (size_t)b * 10000;
    for (int idx = tid; idx < 10000; idx += nt) {
        int n = idx / 100, mcol = idx - n * 100;
        cp[idx] = cl[idx] + ((n == mcol) ? lam : 0.f);
    }
}

// ---------------------------------------------------------------------------
// out[id] = sym( W[wi] @ X[xi] @ W[wi]^T )
// id = b*cout + co ; Xp = X + b*xbstride + (xcbase + co%cin)*NI*NI
// wi = per_matrix ? id : co
// ---------------------------------------------------------------------------
template <int NI, int NO>
__global__ void __launch_bounds__(256) triple_kernel(
    const float* __restrict__ W, const float* __restrict__ X,
    float* __restrict__ out, int cin, int cout, int per_matrix,
    int xbstride, int xcbase)
{
    __shared__ float Xs[NI * NI];
    __shared__ float T1[NO * NI];
    __shared__ float Ys[NO * NO];
    const int tid = threadIdx.x, nt = blockDim.x;
    const int id = blockIdx.x;
    const int b = id / cout, co = id - b * cout;
    const float* Xp = X + (size_t)b * xbstride + (size_t)(xcbase + (co % cin)) * NI * NI;
    const float* Wp = W + (size_t)(per_matrix ? id : co) * NO * NI;

    for (int idx = tid; idx < NI * NI; idx += nt) Xs[idx] = Xp[idx];
    __syncthreads();
    for (int idx = tid; idx < NO * NI; idx += nt) {
        int r = idx / NI, k = idx - r * NI;
        const float* wr = Wp + (size_t)r * NI;
        float acc = 0.f;
        #pragma unroll 4
        for (int j = 0; j < NI; ++j) acc += wr[j] * Xs[j * NI + k];
        T1[idx] = acc;
    }
    __syncthreads();
    for (int idx = tid; idx < NO * NO; idx += nt) {
        int r = idx / NO, c2 = idx - r * NO;
        const float* t1r = T1 + (size_t)r * NI;
        const float* wc = Wp + (size_t)c2 * NI;
        float acc = 0.f;
        #pragma unroll 4
        for (int k = 0; k < NI; ++k) acc += t1r[k] * wc[k];
        Ys[idx] = acc;
    }
    __syncthreads();
    float* Op = out + (size_t)id * NO * NO;
    for (int idx = tid; idx < NO * NO; idx += nt) {
        int r = idx / NO, c2 = idx - r * NO;
        Op[idx] = 0.5f * (Ys[idx] + Ys[c2 * NO + r]);
    }
}

// ---------------------------------------------------------------------------
// out[c] = mean_b in[b,c,:]   in: (B,C,nn); grid = C*chunks
// ---------------------------------------------------------------------------
__global__ void __launch_bounds__(256) mean_kernel(
    const float* __restrict__ in, float* __restrict__ out, int B, int C, int nn,
    int chunks)
{
    const int c = blockIdx.x / chunks, ch = blockIdx.x % chunks;
    const int len = (nn + chunks - 1) / chunks;
    const int lo = ch * len;
    const int hi = (lo + len < nn) ? lo + len : nn;
    for (int idx = lo + threadIdx.x; idx < hi; idx += blockDim.x) {
        float acc = 0.f;
        for (int b = 0; b < B; ++b) acc += in[((size_t)b * C + c) * nn + idx];
        out[(size_t)c * nn + idx] = acc * (1.0f / 64.0f);
    }
}

// ---------------------------------------------------------------------------
// Batched cyclic Jacobi eig + spectral reconstruction.
// Closed-form round-robin pairing (circle method), 3 barriers/round.
// src_off  = (mat/C)*src_bstride + (src_cbase + mat%C)*N*N
// out_off  = ((mat/C)%bmod)*out_bstride + (cbase + ((mat/C)/bmod)*C + mat%C)*N*N
// ---------------------------------------------------------------------------
template <int N, int NT>
__global__ void __launch_bounds__(NT) jacobi_kernel(
    const float* __restrict__ src, int src_bstride, int src_cbase,
    float* __restrict__ out1, int f1,
    float* __restrict__ out2, int f2,
    int out_bstride, int cbase, int C, int bmod)
{
    constexpr int M = N / 2;
    constexpr int L = N - 1;       // rotating players
    constexpr int LD = N + 1;
    __shared__ float A[N * LD];
    __shared__ float V[N * LD];
    __shared__ float cs_[M], sn_[M];
    __shared__ float raww[N], fw[N];
    __shared__ float red[NT];
    __shared__ int anyrot;

    const int tid = threadIdx.x;
    const int mat = blockIdx.x;
    const int bb = mat / C, cc = mat - bb * C;
    const float* Sp = src + (size_t)bb * src_bstride + (size_t)(src_cbase + cc) * N * N;

    float sq = 0.f;
    for (int idx = tid; idx < N * N; idx += NT) {
        int i = idx / N, j = idx - i * N;
        float v = 0.5f * (Sp[idx] + Sp[j * N + i]);
        A[i * LD + j] = v;
        V[i * LD + j] = (i == j) ? 1.f : 0.f;
        sq += v * v;
    }
    red[tid] = sq; __syncthreads();
    for (int s = NT >> 1; s > 0; s >>= 1) {
        if (tid < s) red[tid] += red[tid + s];
        __syncthreads();
    }
    const float tf = 1e-7f * sqrtf(red[0]);

    for (int sweep = 0; sweep < 16; ++sweep) {
        if (tid == 0) anyrot = 0;
        __syncthreads();
        for (int r = 0; r < L; ++r) {
            // phase 1: rotation params (closed-form pairing)
            if (tid < M) {
                int p, q;
                if (tid == 0) { p = r % L; q = N - 1; }
                else { p = (r + tid) % L; q = (r - tid + L) % L; }
                float app = A[p * LD + p], aqq = A[q * LD + q], apq = A[p * LD + q];
                float c = 1.f, s = 0.f;
                float thr = fmaxf(2.5e-7f * sqrtf(fabsf(app * aqq)), tf);
                if (fabsf(apq) > thr) {
                    anyrot = 1;
                    float tau = (aqq - app) / (2.f * apq);
                    float den = fabsf(tau) + sqrtf(1.f + tau * tau);
                    float t = ((tau >= 0.f) ? 1.f : -1.f) / den;
                    c = 1.f / sqrtf(1.f + t * t);
                    s = t * c;
                }
                cs_[tid] = c; sn_[tid] = s;
            }
            __syncthreads();
            // phase 2: rows  A <- J^T A
            for (int idx = tid; idx < M * N; idx += NT) {
                int i = idx / N, j = idx - i * N;
                float s = sn_[i];
                if (s != 0.f) {
                    float c = cs_[i];
                    int p, q;
                    if (i == 0) { p = r % L; q = N - 1; }
                    else { p = (r + i) % L; q = (r - i + L) % L; }
                    float ap = A[p * LD + j], aq = A[q * LD + j];
                    A[p * LD + j] = c * ap - s * aq;
                    A[q * LD + j] = s * ap + c * aq;
                }
            }
            __syncthreads();
            // phase 3: cols  A <- A J ; V <- V J
            for (int idx = tid; idx < M * N; idx += NT) {
                int i = idx / N, j = idx - i * N;
                float s = sn_[i];
                if (s != 0.f) {
                    float c = cs_[i];
                    int p, q;
                    if (i == 0) { p = r % L; q = N - 1; }
                    else { p = (r + i) % L; q = (r - i + L) % L; }
                    float ap = A[j * LD + p], aq = A[j * LD + q];
                    A[j * LD + p] = c * ap - s * aq;
                    A[j * LD + q] = s * ap + c * aq;
                    float vp = V[j * LD + p], vq = V[j * LD + q];
                    V[j * LD + p] = c * vp - s * vq;
                    V[j * LD + q] = s * vp + c * vq;
                }
            }
            __syncthreads();
        }
        int done = (anyrot == 0);
        __syncthreads();
        if (done) break;
    }

    for (int idx = tid; idx < N; idx += NT) raww[idx] = A[idx * LD + idx];
    __syncthreads();

    const int gg = bb / bmod, bbb = bb - gg * bmod;
    // output 1
    for (int idx = tid; idx < N; idx += NT) fw[idx] = eig_apply(raww[idx], f1);
    __syncthreads();
    for (int idx = tid; idx < N * N; idx += NT) {
        int i = idx / N, k = idx - i * N;
        A[i * LD + k] = V[i * LD + k] * fw[k];
    }
    __syncthreads();
    {
        float* o = out1 + (size_t)bbb * out_bstride + (size_t)(cbase + gg * C + cc) * N * N;
        for (int idx = tid; idx < N * N; idx += NT) {
            int i = idx / N, j = idx - i * N;
            float acc = 0.f;
            #pragma unroll 4
            for (int k = 0; k < N; ++k) acc += A[i * LD + k] * V[j * LD + k];
            o[idx] = acc;
        }
    }
    if (out2) {
        __syncthreads();
        for (int idx = tid; idx < N; idx += NT) fw[idx] = eig_apply(raww[idx], f2);
        __syncthreads();
        for (int idx = tid; idx < N * N; idx += NT) {
            int i = idx / N, k = idx - i * N;
            A[i * LD + k] = V[i * LD + k] * fw[k];
        }
        __syncthreads();
        float* o = out2 + (size_t)bbb * out_bstride + (size_t)(cbase + gg * C + cc) * N * N;
        for (int idx = tid; idx < N * N; idx += NT) {
            int i = idx / N, j = idx - i * N;
            float acc = 0.f;
            #pragma unroll 4
            for (int k = 0; k < N; ++k) acc += A[i * LD + k] * V[j * LD + k];
            o[idx] = acc;
        }
    }
}

// ---------------------------------------------------------------------------
// out[b,n] = sum_k Lc[b,k]*cls_w[n,k] + cls_b[n]
// ---------------------------------------------------------------------------
__global__ void __launch_bounds__(256) head_kernel(
    const float* __restrict__ Lc, const float* __restrict__ cw,
    const float* __restrict__ cb, float* __restrict__ out)
{
    __shared__ float row[20000];
    const int b = blockIdx.x, tid = threadIdx.x, nt = blockDim.x;
    const float* lp = Lc + (size_t)b * 20000;
    for (int i = tid; i < 20000; i += nt) row[i] = lp[i];
    __syncthreads();
    if (tid < 100) {
        float acc = cb[tid];
        const float* wr = cw + (size_t)tid * 20000;
        #pragma unroll 4
        for (int k = 0; k < 20000; ++k) acc += row[k] * wr[k];
        out[b * 100 + tid] = acc;
    }
}

// ---------------------------------------------------------------------------
extern "C" void kernel_launch(void* const* d_in, const int* in_sizes, int n_in,
                              void* d_out, int out_size, void* d_ws, size_t ws_size,
                              hipStream_t stream)
{
    const float* x      = (const float*)d_in[0];
    const float* fc_w   = (const float*)d_in[1];
    const float* fc_b   = (const float*)d_in[2];
    const float* stem_w = (const float*)d_in[3];
    const float* pre0_w = (const float*)d_in[4];
    const float* pre1_w = (const float*)d_in[5];
    const float* wr0    = (const float*)d_in[6];
    const float* wr1    = (const float*)d_in[7];
    const float* wn2    = (const float*)d_in[8];
    const float* wn4    = (const float*)d_in[9];
    const float* wn7    = (const float*)d_in[10];
    const float* cls_w  = (const float*)d_in[11];
    const float* cls_b  = (const float*)d_in[12];
    float* out = (float*)d_out;
    float* ws  = (float*)d_ws;

    const int BIG = 1 << 28;

    // workspace: A0 [0, 2.56M), A1 [2.56M, 5.12M), smalls [5.12M, 5.26M)
    float* A0    = ws + 0;
    float* A1    = ws + 2560000;
    float* Mm    = ws + 5120000;  // up to (4,100,100)
    float* Gi    = ws + 5160000;  // up to (4,100,100)
    float* Wcat  = ws + 5200000;  // (4,100,100)
    float* Wrcat = ws + 5240000;  // (4,50,100)

    // weight concats (branch merge)
    hipMemcpyAsync(Wcat,          pre0_w, 20000 * 4, hipMemcpyDeviceToDevice, stream);
    hipMemcpyAsync(Wcat + 20000,  pre1_w, 20000 * 4, hipMemcpyDeviceToDevice, stream);
    hipMemcpyAsync(Wrcat,         wr0,    10000 * 4, hipMemcpyDeviceToDevice, stream);
    hipMemcpyAsync(Wrcat + 10000, wr1,    10000 * 4, hipMemcpyDeviceToDevice, stream);

    // features + covariance
    float* F   = A0;              // (64,100,100)
    float* COV = A1;              // (64,100,100)
    fc_kernel<<<dim3(6400), dim3(128), 0, stream>>>(x, fc_w, fc_b, F);
    cov_kernel<<<dim3(64), dim3(256), 0, stream>>>(F, COV);

    // stem: s = batchnorm_spd(bimap(cov, stem_w))
    float* Y1 = A0;               // (64,100,100), overwrites F (dead)
    triple_kernel<100,100><<<dim3(64), dim3(256), 0, stream>>>(stem_w, COV, Y1, 1, 1, 0, 10000, 0);
    float* L1 = A1;               // overwrites COV (dead)
    jacobi_kernel<100,256><<<dim3(64), dim3(256), 0, stream>>>(Y1, 10000, 0, L1, F_LOG, nullptr, 0, 10000, 0, 1, BIG);
    mean_kernel<<<dim3(16), dim3(256), 0, stream>>>(L1, Mm, 64, 1, 10000, 16);
    jacobi_kernel<100,256><<<dim3(1), dim3(256), 0, stream>>>(Mm, 10000, 0, Gi, F_INVSQRTEXP, nullptr, 0, 10000, 0, 1, BIG);
    float* Sst = A1;              // overwrites L1 (dead)
    triple_kernel<100,100><<<dim3(64), dim3(256), 0, stream>>>(Gi, Y1, Sst, 1, 1, 0, 10000, 0);

    // r = reeig(s)
    float* R = A0;                // overwrites Y1 (dead)
    jacobi_kernel<100,256><<<dim3(64), dim3(256), 0, stream>>>(Sst, 10000, 0, R, F_CLIP, nullptr, 0, 10000, 0, 1, BIG);

    // merged branches 0+1: Y4 = bimap(r, Wcat) -> (64,4,100,100)
    float* Y4 = A1;
    triple_kernel<100,100><<<dim3(256), dim3(256), 0, stream>>>(Wcat, R, Y4, 1, 4, 0, 10000, 0);
    float* L4 = A0;               // overwrites R (dead)
    jacobi_kernel<100,256><<<dim3(256), dim3(256), 0, stream>>>(Y4, 40000, 0, L4, F_LOG, nullptr, 0, 40000, 0, 4, BIG);
    mean_kernel<<<dim3(64), dim3(256), 0, stream>>>(L4, Mm, 64, 4, 10000, 16);
    jacobi_kernel<100,256><<<dim3(4), dim3(256), 0, stream>>>(Mm, 40000, 0, Gi, F_INVSQRTEXP, nullptr, 0, 40000, 0, 4, BIG);
    float* S01 = A0;              // (64,4,100,100), overwrites L4 (dead)
    triple_kernel<100,100><<<dim3(256), dim3(256), 0, stream>>>(Gi, Y4, S01, 4, 4, 0, 40000, 0);

    // bAB = bimap over Wrcat: ch0-1 = bimap(s0,wr0), ch2-3 = bimap(s1,wr1)
    float* bAB = A1;              // (64,4,50,50) = 640k
    triple_kernel<100,50><<<dim3(256), dim3(256), 0, stream>>>(Wrcat, S01, bAB, 4, 4, 0, 40000, 0);

    float* bAs  = A0 + 320000;    // (64,2,50,50)
    float* bAis = A0 + 640000;
    float* bIn  = A0 + 960000;
    float* bSi  = A0 + 1280000;
    float* T0   = A0;             // bimap temp (64,2,50,50)
    float* s2b  = A1 + 640000;    // states 2..5, contiguous
    float* s3b  = A1 + 960000;
    float* s4b  = A1 + 1280000;
    float* s5b  = A1 + 1600000;

    // states[2] = bary2(bAB[0:2], bAB[2:4])
    jacobi_kernel<50,128><<<dim3(128), dim3(128), 0, stream>>>(bAB, 10000, 0, bAs, F_SQRT, bAis, F_INVSQRT, 5000, 0, 2, BIG);
    triple_kernel<50,50><<<dim3(128), dim3(256), 0, stream>>>(bAis, bAB, bIn, 2, 2, 1, 10000, 2);
    jacobi_kernel<50,128><<<dim3(128), dim3(128), 0, stream>>>(bIn, 5000, 0, bSi, F_SQRT, nullptr, 0, 5000, 0, 2, BIG);
    triple_kernel<50,50><<<dim3(128), dim3(256), 0, stream>>>(bAs, bSi, s2b, 2, 2, 1, 5000, 0);

    // states[3] = bary2(bimap(s2,wn2), s2)
    triple_kernel<50,50><<<dim3(128), dim3(256), 0, stream>>>(wn2, s2b, T0, 2, 2, 0, 5000, 0);
    jacobi_kernel<50,128><<<dim3(128), dim3(128), 0, stream>>>(T0, 5000, 0, bAs, F_SQRT, bAis, F_INVSQRT, 5000, 0, 2, BIG);
    triple_kernel<50,50><<<dim3(128), dim3(256), 0, stream>>>(bAis, s2b, bIn, 2, 2, 1, 5000, 0);
    jacobi_kernel<50,128><<<dim3(128), dim3(128), 0, stream>>>(bIn, 5000, 0, bSi, F_SQRT, nullptr, 0, 5000, 0, 2, BIG);
    triple_kernel<50,50><<<dim3(128), dim3(256), 0, stream>>>(bAs, bSi, s3b, 2, 2, 1, 5000, 0);

    // states[4] = bary2(bimap(s3,wn4), s2)
    triple_kernel<50,50><<<dim3(128), dim3(256), 0, stream>>>(wn4, s3b, T0, 2, 2, 0, 5000, 0);
    jacobi_kernel<50,128><<<dim3(128), dim3(128), 0, stream>>>(T0, 5000, 0, bAs, F_SQRT, bAis, F_INVSQRT, 5000, 0, 2, BIG);
    triple_kernel<50,50><<<dim3(128), dim3(256), 0, stream>>>(bAis, s2b, bIn, 2, 2, 1, 5000, 0);
    jacobi_kernel<50,128><<<dim3(128), dim3(128), 0, stream>>>(bIn, 5000, 0, bSi, F_SQRT, nullptr, 0, 5000, 0, 2, BIG);
    triple_kernel<50,50><<<dim3(128), dim3(256), 0, stream>>>(bAs, bSi, s4b, 2, 2, 1, 5000, 0);

    // states[5] = bary2(s4, bimap(s3,wn7))
    triple_kernel<50,50><<<dim3(128), dim3(256), 0, stream>>>(wn7, s3b, T0, 2, 2, 0, 5000, 0);
    jacobi_kernel<50,128><<<dim3(128), dim3(128), 0, stream>>>(s4b, 5000, 0, bAs, F_SQRT, bAis, F_INVSQRT, 5000, 0, 2, BIG);
    triple_kernel<50,50><<<dim3(128), dim3(256), 0, stream>>>(bAis, T0, bIn, 2, 2, 1, 5000, 0);
    jacobi_kernel<50,128><<<dim3(128), dim3(128), 0, stream>>>(bIn, 5000, 0, bSi, F_SQRT, nullptr, 0, 5000, 0, 2, BIG);
    triple_kernel<50,50><<<dim3(128), dim3(256), 0, stream>>>(bAs, bSi, s5b, 2, 2, 1, 5000, 0);

    // merged logm of states[2:6] -> Lc (64, 8, 50, 50)
    float* Lc = A0;               // 1.28M floats, all A0 temps dead
    jacobi_kernel<50,128><<<dim3(512), dim3(128), 0, stream>>>(s2b, 5000, 0, Lc, F_LOG, nullptr, 0, 20000, 0, 2, 64);

    // head
    head_kernel<<<dim3(64), dim3(256), 0, stream>>>(Lc, cls_w, cls_b, out);
}

// Round 3
// 21271.944 us; speedup vs baseline: 2.9845x; 2.2205x over previous
//
#include <hip/hip_runtime.h>
#include <math.h>

#define EPSF   1e-6f
#define REEPS  1e-4f

enum EigFn { F_LOG = 0, F_SQRT = 1, F_INVSQRT = 2, F_CLIP = 3 };

__device__ __forceinline__ float eig_apply(float w, int f) {
    switch (f) {
        case F_LOG:     return logf(fmaxf(w, EPSF));
        case F_SQRT:    return sqrtf(fmaxf(w, EPSF));
        case F_INVSQRT: return 1.0f / sqrtf(fmaxf(w, EPSF));
        case F_CLIP:    return fmaxf(w, REEPS);
        default:        return w;
    }
}

// ---------------------------------------------------------------------------
// f[b,t,n] = sum_k x[b,k,t]*fc_w[n,k] + fc_b[n], centered over n
// ---------------------------------------------------------------------------
__global__ void __launch_bounds__(128) fc_kernel(
    const float* __restrict__ x, const float* __restrict__ fcw,
    const float* __restrict__ fcb, float* __restrict__ f)
{
    __shared__ float xc[512];
    __shared__ float fv[100];
    __shared__ float red[128];
    const int bt = blockIdx.x;
    const int b = bt / 100, t = bt % 100;
    const int tid = threadIdx.x, nt = blockDim.x;

    for (int k = tid; k < 512; k += nt)
        xc[k] = x[(size_t)b * 51200 + (size_t)k * 100 + t];
    __syncthreads();

    float val = 0.f;
    if (tid < 100) {
        float acc = fcb[tid];
        const float* wr = fcw + (size_t)tid * 512;
        #pragma unroll 8
        for (int k = 0; k < 512; ++k) acc += xc[k] * wr[k];
        val = acc;
        fv[tid] = acc;
    }
    __syncthreads();
    float part = 0.f;
    for (int i = tid; i < 100; i += nt) part += fv[i];
    red[tid] = part; __syncthreads();
    for (int s = nt >> 1; s > 0; s >>= 1) {
        if (tid < s) red[tid] += red[tid + s];
        __syncthreads();
    }
    float m = red[0] * 0.01f;
    if (tid < 100)
        f[(size_t)b * 10000 + t * 100 + tid] = val - m;
}

// ---------------------------------------------------------------------------
// cov[b] = f[b]^T f[b] / 99 + 1e-5*trace*I
// ---------------------------------------------------------------------------
__global__ void __launch_bounds__(256) cov_kernel(
    const float* __restrict__ f, float* __restrict__ cov)
{
    __shared__ float fl[10000];
    __shared__ float cl[10000];
    __shared__ float red[256];
    const int b = blockIdx.x, tid = threadIdx.x, nt = blockDim.x;
    const float* fp = f + (size_t)b * 10000;
    for (int i = tid; i < 10000; i += nt) fl[i] = fp[i];
    __syncthreads();
    for (int idx = tid; idx < 10000; idx += nt) {
        int n = idx / 100, mcol = idx - n * 100;
        float acc = 0.f;
        #pragma unroll 4
        for (int t = 0; t < 100; ++t) acc += fl[t * 100 + n] * fl[t * 100 + mcol];
        cl[idx] = acc * (1.0f / 99.0f);
    }
    __syncthreads();
    float tr = 0.f;
    for (int i = tid; i < 100; i += nt) tr += cl[i * 100 + i];
    red[tid] = tr; __syncthreads();
    for (int s = nt >> 1; s > 0; s >>= 1) {
        if (tid < s) red[tid] += red[tid + s];
        __syncthreads();
    }
    float lam = red[0] * 1e-5f;
    float* cp = cov + (size_t)b * 10000;
    for (int idx = tid; idx < 10000; idx += nt) {
        int n = idx / 100, mcol = idx - n * 100;
        cp[idx] = cl[idx] + ((n == mcol) ? lam : 0.f);
    }
}

// ---------------------------------------------------------------------------
// out[id] = sym( W[wi] @ X[xi] @ W[wi]^T )
// ---------------------------------------------------------------------------
template <int NI, int NO>
__global__ void __launch_bounds__(256) triple_kernel(
    const float* __restrict__ W, const float* __restrict__ X,
    float* __restrict__ out, int cin, int cout, int per_matrix,
    int xbstride, int xcbase)
{
    __shared__ float Xs[NI * NI];
    __shared__ float T1[NO * NI];
    __shared__ float Ys[NO * NO];
    const int tid = threadIdx.x, nt = blockDim.x;
    const int id = blockIdx.x;
    const int b = id / cout, co = id - b * cout;
    const float* Xp = X + (size_t)b * xbstride + (size_t)(xcbase + (co % cin)) * NI * NI;
    const float* Wp = W + (size_t)(per_matrix ? id : co) * NO * NI;

    for (int idx = tid; idx < NI * NI; idx += nt) Xs[idx] = Xp[idx];
    __syncthreads();
    for (int idx = tid; idx < NO * NI; idx += nt) {
        int r = idx / NI, k = idx - r * NI;
        const float* wr = Wp + (size_t)r * NI;
        float acc = 0.f;
        #pragma unroll 4
        for (int j = 0; j < NI; ++j) acc += wr[j] * Xs[j * NI + k];
        T1[idx] = acc;
    }
    __syncthreads();
    for (int idx = tid; idx < NO * NO; idx += nt) {
        int r = idx / NO, c2 = idx - r * NO;
        const float* t1r = T1 + (size_t)r * NI;
        const float* wc = Wp + (size_t)c2 * NI;
        float acc = 0.f;
        #pragma unroll 4
        for (int k = 0; k < NI; ++k) acc += t1r[k] * wc[k];
        Ys[idx] = acc;
    }
    __syncthreads();
    float* Op = out + (size_t)id * NO * NO;
    for (int idx = tid; idx < NO * NO; idx += nt) {
        int r = idx / NO, c2 = idx - r * NO;
        Op[idx] = 0.5f * (Ys[idx] + Ys[c2 * NO + r]);
    }
}

// ---------------------------------------------------------------------------
// out[c] = mean_b in[b,c,:]   in: (B,C,nn); grid = C*chunks
// ---------------------------------------------------------------------------
__global__ void __launch_bounds__(256) mean_kernel(
    const float* __restrict__ in, float* __restrict__ out, int B, int C, int nn,
    int chunks)
{
    const int c = blockIdx.x / chunks, ch = blockIdx.x % chunks;
    const int len = (nn + chunks - 1) / chunks;
    const int lo = ch * len;
    const int hi = (lo + len < nn) ? lo + len : nn;
    for (int idx = lo + threadIdx.x; idx < hi; idx += blockDim.x) {
        float acc = 0.f;
        for (int b = 0; b < B; ++b) acc += in[((size_t)b * C + c) * nn + idx];
        out[(size_t)c * nn + idx] = acc * (1.0f / 64.0f);
    }
}

// ---------------------------------------------------------------------------
// C = scale*(A @ B) + addI*I for symmetric A,B held in LDS (row-dot form).
// Thread tile: 4 rows x 10 cols; requires N % 20 == 0, LD % 4 == 0.
// ---------------------------------------------------------------------------
template <int N, int LD>
__device__ __forceinline__ void symm_mm(const float* A_, const float* B_,
                                        float* C_, float scale, float addI,
                                        int tid)
{
    constexpr int RG = N / 4;
    constexpr int CG = N / 10;
    if (tid < RG * CG) {
        const int rg = tid % RG, cg = tid / RG;
        const int r0 = rg * 4, c0 = cg * 10;
        float acc[4][10];
        #pragma unroll
        for (int i = 0; i < 4; ++i)
            #pragma unroll
            for (int j = 0; j < 10; ++j) acc[i][j] = 0.f;
        for (int k0 = 0; k0 < N; k0 += 4) {
            float4 a[4], b[10];
            #pragma unroll
            for (int i = 0; i < 4; ++i)
                a[i] = *(const float4*)(A_ + (r0 + i) * LD + k0);
            #pragma unroll
            for (int j = 0; j < 10; ++j)
                b[j] = *(const float4*)(B_ + (c0 + j) * LD + k0);
            #pragma unroll
            for (int i = 0; i < 4; ++i)
                #pragma unroll
                for (int j = 0; j < 10; ++j)
                    acc[i][j] += a[i].x * b[j].x + a[i].y * b[j].y
                               + a[i].z * b[j].z + a[i].w * b[j].w;
        }
        #pragma unroll
        for (int i = 0; i < 4; ++i)
            #pragma unroll
            for (int j = 0; j < 10; ++j) {
                int r = r0 + i, c = c0 + j;
                C_[r * LD + c] = scale * acc[i][j] + ((r == c) ? addI : 0.f);
            }
    }
}

// ---------------------------------------------------------------------------
// dst[blk] = expm(alpha * sym(src[blk]))  via scaling-and-squaring + Taylor-8.
// All intermediates are polynomials in one symmetric matrix -> symmetric.
// ---------------------------------------------------------------------------
template <int N>
__global__ void __launch_bounds__(256) expm_kernel(
    const float* __restrict__ src, float* __restrict__ dst, float alpha)
{
    constexpr int LD = N + 4;           // 104: float4-aligned rows
    __shared__ float Bs[N * LD];
    __shared__ float T0[N * LD];
    __shared__ float T1[N * LD];
    __shared__ float red[256];
    __shared__ int kshare;
    const int tid = threadIdx.x;
    const float* Sp = src + (size_t)blockIdx.x * N * N;
    float* Dp = dst + (size_t)blockIdx.x * N * N;

    float sq = 0.f;
    for (int idx = tid; idx < N * N; idx += 256) {
        int i = idx / N, j = idx - i * N;
        float v = alpha * 0.5f * (Sp[idx] + Sp[j * N + i]);
        Bs[i * LD + j] = v;
        sq += v * v;
    }
    red[tid] = sq; __syncthreads();
    for (int s = 128; s > 0; s >>= 1) {
        if (tid < s) red[tid] += red[tid + s];
        __syncthreads();
    }
    if (tid == 0) {
        float nf = sqrtf(red[0]);
        int k = 0;
        if (nf > 0.25f) {
            k = (int)ceilf(log2f(nf * 4.0f));
            if (k < 0) k = 0;
            if (k > 20) k = 20;
        }
        kshare = k;
    }
    __syncthreads();
    const int k = kshare;
    const float scl = exp2f(-(float)k);
    constexpr int M_ORD = 8;
    for (int idx = tid; idx < N * N; idx += 256) {
        int i = idx / N, j = idx - i * N;
        float b = Bs[i * LD + j] * scl;
        Bs[i * LD + j] = b;
        T0[i * LD + j] = b * (1.0f / M_ORD) + ((i == j) ? 1.f : 0.f);
    }
    __syncthreads();
    float* Tcur = T0; float* Tnext = T1;
    for (int j = M_ORD - 1; j >= 1; --j) {       // Horner: T = I + B*T/j
        symm_mm<N, LD>(Bs, Tcur, Tnext, 1.0f / (float)j, 1.0f, tid);
        __syncthreads();
        float* t = Tcur; Tcur = Tnext; Tnext = t;
    }
    for (int s = 0; s < k; ++s) {                // repeated squaring
        symm_mm<N, LD>(Tcur, Tcur, Tnext, 1.0f, 0.0f, tid);
        __syncthreads();
        float* t = Tcur; Tcur = Tnext; Tnext = t;
    }
    for (int idx = tid; idx < N * N; idx += 256) {
        int i = idx / N, j = idx - i * N;
        Dp[idx] = Tcur[i * LD + j];
    }
}

// ---------------------------------------------------------------------------
// Batched cyclic Jacobi eig + spectral reconstruction.
// Closed-form round-robin pairing, 3 barriers/round.
// src_off = (mat/C)*src_bstride + (src_cbase + mat%C)*N*N
// out_off = ((mat/C)%bmod)*out_bstride + (cbase + ((mat/C)/bmod)*C + mat%C)*N*N
// ---------------------------------------------------------------------------
template <int N, int NT>
__global__ void __launch_bounds__(NT) jacobi_kernel(
    const float* __restrict__ src, int src_bstride, int src_cbase,
    float* __restrict__ out1, int f1,
    float* __restrict__ out2, int f2,
    int out_bstride, int cbase, int C, int bmod)
{
    constexpr int M = N / 2;
    constexpr int L = N - 1;
    constexpr int LD = N + 1;
    __shared__ float A[N * LD];
    __shared__ float V[N * LD];
    __shared__ float cs_[M], sn_[M];
    __shared__ float raww[N], fw[N];
    __shared__ float red[NT];
    __shared__ int anyrot;

    const int tid = threadIdx.x;
    const int mat = blockIdx.x;
    const int bb = mat / C, cc = mat - bb * C;
    const float* Sp = src + (size_t)bb * src_bstride + (size_t)(src_cbase + cc) * N * N;

    float sq = 0.f;
    for (int idx = tid; idx < N * N; idx += NT) {
        int i = idx / N, j = idx - i * N;
        float v = 0.5f * (Sp[idx] + Sp[j * N + i]);
        A[i * LD + j] = v;
        V[i * LD + j] = (i == j) ? 1.f : 0.f;
        sq += v * v;
    }
    red[tid] = sq; __syncthreads();
    for (int s = NT >> 1; s > 0; s >>= 1) {
        if (tid < s) red[tid] += red[tid + s];
        __syncthreads();
    }
    // floor ABOVE fp32 rotation round-off (1.2e-7*||A||) so we terminate
    const float tf = 3e-7f * sqrtf(red[0]);

    for (int sweep = 0; sweep < 12; ++sweep) {
        if (tid == 0) anyrot = 0;
        __syncthreads();
        for (int r = 0; r < L; ++r) {
            if (tid < M) {
                int p, q;
                if (tid == 0) { p = r % L; q = N - 1; }
                else { p = (r + tid) % L; q = (r - tid + L) % L; }
                float app = A[p * LD + p], aqq = A[q * LD + q], apq = A[p * LD + q];
                float c = 1.f, s = 0.f;
                float thr = fmaxf(2.5e-7f * sqrtf(fabsf(app * aqq)), tf);
                if (fabsf(apq) > thr) {
                    anyrot = 1;
                    float tau = (aqq - app) / (2.f * apq);
                    float den = fabsf(tau) + sqrtf(1.f + tau * tau);
                    float t = ((tau >= 0.f) ? 1.f : -1.f) / den;
                    c = 1.f / sqrtf(1.f + t * t);
                    s = t * c;
                }
                cs_[tid] = c; sn_[tid] = s;
            }
            __syncthreads();
            for (int idx = tid; idx < M * N; idx += NT) {
                int i = idx / N, j = idx - i * N;
                float s = sn_[i];
                if (s != 0.f) {
                    float c = cs_[i];
                    int p, q;
                    if (i == 0) { p = r % L; q = N - 1; }
                    else { p = (r + i) % L; q = (r - i + L) % L; }
                    float ap = A[p * LD + j], aq = A[q * LD + j];
                    A[p * LD + j] = c * ap - s * aq;
                    A[q * LD + j] = s * ap + c * aq;
                }
            }
            __syncthreads();
            for (int idx = tid; idx < M * N; idx += NT) {
                int i = idx / N, j = idx - i * N;
                float s = sn_[i];
                if (s != 0.f) {
                    float c = cs_[i];
                    int p, q;
                    if (i == 0) { p = r % L; q = N - 1; }
                    else { p = (r + i) % L; q = (r - i + L) % L; }
                    float ap = A[j * LD + p], aq = A[j * LD + q];
                    A[j * LD + p] = c * ap - s * aq;
                    A[j * LD + q] = s * ap + c * aq;
                    float vp = V[j * LD + p], vq = V[j * LD + q];
                    V[j * LD + p] = c * vp - s * vq;
                    V[j * LD + q] = s * vp + c * vq;
                }
            }
            __syncthreads();
        }
        int done = (anyrot == 0);
        __syncthreads();
        if (done) break;
    }

    for (int idx = tid; idx < N; idx += NT) raww[idx] = A[idx * LD + idx];
    __syncthreads();

    const int gg = bb / bmod, bbb = bb - gg * bmod;
    for (int idx = tid; idx < N; idx += NT) fw[idx] = eig_apply(raww[idx], f1);
    __syncthreads();
    for (int idx = tid; idx < N * N; idx += NT) {
        int i = idx / N, k = idx - i * N;
        A[i * LD + k] = V[i * LD + k] * fw[k];
    }
    __syncthreads();
    {
        float* o = out1 + (size_t)bbb * out_bstride + (size_t)(cbase + gg * C + cc) * N * N;
        for (int idx = tid; idx < N * N; idx += NT) {
            int i = idx / N, j = idx - i * N;
            float acc = 0.f;
            #pragma unroll 4
            for (int k = 0; k < N; ++k) acc += A[i * LD + k] * V[j * LD + k];
            o[idx] = acc;
        }
    }
    if (out2) {
        __syncthreads();
        for (int idx = tid; idx < N; idx += NT) fw[idx] = eig_apply(raww[idx], f2);
        __syncthreads();
        for (int idx = tid; idx < N * N; idx += NT) {
            int i = idx / N, k = idx - i * N;
            A[i * LD + k] = V[i * LD + k] * fw[k];
        }
        __syncthreads();
        float* o = out2 + (size_t)bbb * out_bstride + (size_t)(cbase + gg * C + cc) * N * N;
        for (int idx = tid; idx < N * N; idx += NT) {
            int i = idx / N, j = idx - i * N;
            float acc = 0.f;
            #pragma unroll 4
            for (int k = 0; k < N; ++k) acc += A[i * LD + k] * V[j * LD + k];
            o[idx] = acc;
        }
    }
}

// ---------------------------------------------------------------------------
// out[b,n] = sum_k Lc[b,k]*cls_w[n,k] + cls_b[n]
// ---------------------------------------------------------------------------
__global__ void __launch_bounds__(256) head_kernel(
    const float* __restrict__ Lc, const float* __restrict__ cw,
    const float* __restrict__ cb, float* __restrict__ out)
{
    __shared__ float row[20000];
    const int b = blockIdx.x, tid = threadIdx.x, nt = blockDim.x;
    const float* lp = Lc + (size_t)b * 20000;
    for (int i = tid; i < 20000; i += nt) row[i] = lp[i];
    __syncthreads();
    if (tid < 100) {
        float acc = cb[tid];
        const float* wr = cw + (size_t)tid * 20000;
        #pragma unroll 4
        for (int k = 0; k < 20000; ++k) acc += row[k] * wr[k];
        out[b * 100 + tid] = acc;
    }
}

// ---------------------------------------------------------------------------
extern "C" void kernel_launch(void* const* d_in, const int* in_sizes, int n_in,
                              void* d_out, int out_size, void* d_ws, size_t ws_size,
                              hipStream_t stream)
{
    const float* x      = (const float*)d_in[0];
    const float* fc_w   = (const float*)d_in[1];
    const float* fc_b   = (const float*)d_in[2];
    const float* stem_w = (const float*)d_in[3];
    const float* pre0_w = (const float*)d_in[4];
    const float* pre1_w = (const float*)d_in[5];
    const float* wr0    = (const float*)d_in[6];
    const float* wr1    = (const float*)d_in[7];
    const float* wn2    = (const float*)d_in[8];
    const float* wn4    = (const float*)d_in[9];
    const float* wn7    = (const float*)d_in[10];
    const float* cls_w  = (const float*)d_in[11];
    const float* cls_b  = (const float*)d_in[12];
    float* out = (float*)d_out;
    float* ws  = (float*)d_ws;

    const int BIG = 1 << 28;

    float* A0    = ws + 0;
    float* A1    = ws + 2560000;
    float* Mm    = ws + 5120000;  // up to (4,100,100)
    float* Gi    = ws + 5160000;  // up to (4,100,100)
    float* Wcat  = ws + 5200000;  // (4,100,100)
    float* Wrcat = ws + 5240000;  // (4,50,100)

    hipMemcpyAsync(Wcat,          pre0_w, 20000 * 4, hipMemcpyDeviceToDevice, stream);
    hipMemcpyAsync(Wcat + 20000,  pre1_w, 20000 * 4, hipMemcpyDeviceToDevice, stream);
    hipMemcpyAsync(Wrcat,         wr0,    10000 * 4, hipMemcpyDeviceToDevice, stream);
    hipMemcpyAsync(Wrcat + 10000, wr1,    10000 * 4, hipMemcpyDeviceToDevice, stream);

    float* F   = A0;
    float* COV = A1;
    fc_kernel<<<dim3(6400), dim3(128), 0, stream>>>(x, fc_w, fc_b, F);
    cov_kernel<<<dim3(64), dim3(256), 0, stream>>>(F, COV);

    // stem: s = batchnorm_spd(bimap(cov, stem_w));  Gi = expm(-mean(logm)/2)
    float* Y1 = A0;
    triple_kernel<100,100><<<dim3(64), dim3(256), 0, stream>>>(stem_w, COV, Y1, 1, 1, 0, 10000, 0);
    float* L1 = A1;
    jacobi_kernel<100,512><<<dim3(64), dim3(512), 0, stream>>>(Y1, 10000, 0, L1, F_LOG, nullptr, 0, 10000, 0, 1, BIG);
    mean_kernel<<<dim3(16), dim3(256), 0, stream>>>(L1, Mm, 64, 1, 10000, 16);
    expm_kernel<100><<<dim3(1), dim3(256), 0, stream>>>(Mm, Gi, -0.5f);
    float* Sst = A1;
    triple_kernel<100,100><<<dim3(64), dim3(256), 0, stream>>>(Gi, Y1, Sst, 1, 1, 0, 10000, 0);

    // r = reeig(s)
    float* R = A0;
    jacobi_kernel<100,512><<<dim3(64), dim3(512), 0, stream>>>(Sst, 10000, 0, R, F_CLIP, nullptr, 0, 10000, 0, 1, BIG);

    // merged branches 0+1
    float* Y4 = A1;
    triple_kernel<100,100><<<dim3(256), dim3(256), 0, stream>>>(Wcat, R, Y4, 1, 4, 0, 10000, 0);
    float* L4 = A0;
    jacobi_kernel<100,512><<<dim3(256), dim3(512), 0, stream>>>(Y4, 40000, 0, L4, F_LOG, nullptr, 0, 40000, 0, 4, BIG);
    mean_kernel<<<dim3(64), dim3(256), 0, stream>>>(L4, Mm, 64, 4, 10000, 16);
    expm_kernel<100><<<dim3(4), dim3(256), 0, stream>>>(Mm, Gi, -0.5f);
    float* S01 = A0;
    triple_kernel<100,100><<<dim3(256), dim3(256), 0, stream>>>(Gi, Y4, S01, 4, 4, 0, 40000, 0);

    // bAB: ch0-1 = bimap(s0,wr0), ch2-3 = bimap(s1,wr1)
    float* bAB = A1;
    triple_kernel<100,50><<<dim3(256), dim3(256), 0, stream>>>(Wrcat, S01, bAB, 4, 4, 0, 40000, 0);

    float* bAs  = A0 + 320000;
    float* bAis = A0 + 640000;
    float* bIn  = A0 + 960000;
    float* bSi  = A0 + 1280000;
    float* T0   = A0;
    float* s2b  = A1 + 640000;
    float* s3b  = A1 + 960000;
    float* s4b  = A1 + 1280000;
    float* s5b  = A1 + 1600000;

    // states[2] = bary2(bAB[0:2], bAB[2:4])
    jacobi_kernel<50,256><<<dim3(128), dim3(256), 0, stream>>>(bAB, 10000, 0, bAs, F_SQRT, bAis, F_INVSQRT, 5000, 0, 2, BIG);
    triple_kernel<50,50><<<dim3(128), dim3(256), 0, stream>>>(bAis, bAB, bIn, 2, 2, 1, 10000, 2);
    jacobi_kernel<50,256><<<dim3(128), dim3(256), 0, stream>>>(bIn, 5000, 0, bSi, F_SQRT, nullptr, 0, 5000, 0, 2, BIG);
    triple_kernel<50,50><<<dim3(128), dim3(256), 0, stream>>>(bAs, bSi, s2b, 2, 2, 1, 5000, 0);

    // states[3] = bary2(bimap(s2,wn2), s2)
    triple_kernel<50,50><<<dim3(128), dim3(256), 0, stream>>>(wn2, s2b, T0, 2, 2, 0, 5000, 0);
    jacobi_kernel<50,256><<<dim3(128), dim3(256), 0, stream>>>(T0, 5000, 0, bAs, F_SQRT, bAis, F_INVSQRT, 5000, 0, 2, BIG);
    triple_kernel<50,50><<<dim3(128), dim3(256), 0, stream>>>(bAis, s2b, bIn, 2, 2, 1, 5000, 0);
    jacobi_kernel<50,256><<<dim3(128), dim3(256), 0, stream>>>(bIn, 5000, 0, bSi, F_SQRT, nullptr, 0, 5000, 0, 2, BIG);
    triple_kernel<50,50><<<dim3(128), dim3(256), 0, stream>>>(bAs, bSi, s3b, 2, 2, 1, 5000, 0);

    // states[4] = bary2(bimap(s3,wn4), s2)
    triple_kernel<50,50><<<dim3(128), dim3(256), 0, stream>>>(wn4, s3b, T0, 2, 2, 0, 5000, 0);
    jacobi_kernel<50,256><<<dim3(128), dim3(256), 0, stream>>>(T0, 5000, 0, bAs, F_SQRT, bAis, F_INVSQRT, 5000, 0, 2, BIG);
    triple_kernel<50,50><<<dim3(128), dim3(256), 0, stream>>>(bAis, s2b, bIn, 2, 2, 1, 5000, 0);
    jacobi_kernel<50,256><<<dim3(128), dim3(256), 0, stream>>>(bIn, 5000, 0, bSi, F_SQRT, nullptr, 0, 5000, 0, 2, BIG);
    triple_kernel<50,50><<<dim3(128), dim3(256), 0, stream>>>(bAs, bSi, s4b, 2, 2, 1, 5000, 0);

    // states[5] = bary2(s4, bimap(s3,wn7))
    triple_kernel<50,50><<<dim3(128), dim3(256), 0, stream>>>(wn7, s3b, T0, 2, 2, 0, 5000, 0);
    jacobi_kernel<50,256><<<dim3(128), dim3(256), 0, stream>>>(s4b, 5000, 0, bAs, F_SQRT, bAis, F_INVSQRT, 5000, 0, 2, BIG);
    triple_kernel<50,50><<<dim3(128), dim3(256), 0, stream>>>(bAis, T0, bIn, 2, 2, 1, 5000, 0);
    jacobi_kernel<50,256><<<dim3(128), dim3(256), 0, stream>>>(bIn, 5000, 0, bSi, F_SQRT, nullptr, 0, 5000, 0, 2, BIG);
    triple_kernel<50,50><<<dim3(128), dim3(256), 0, stream>>>(bAs, bSi, s5b, 2, 2, 1, 5000, 0);

    // merged logm of states[2:6] -> Lc (64, 8, 50, 50)
    float* Lc = A0;
    jacobi_kernel<50,256><<<dim3(512), dim3(256), 0, stream>>>(s2b, 5000, 0, Lc, F_LOG, nullptr, 0, 20000, 0, 2, 64);

    head_kernel<<<dim3(64), dim3(256), 0, stream>>>(Lc, cls_w, cls_b, out);
}